// Round 3
// baseline (492.149 us; speedup 1.0000x reference)
//
#include <hip/hip_runtime.h>
#include <hip/hip_bf16.h>

#define TT 2048
#define HD 1024
#define NE 8
#define ID 2048

typedef short bf16x8 __attribute__((ext_vector_type(8)));
typedef float f32x4 __attribute__((ext_vector_type(4)));

__device__ __forceinline__ unsigned f2bf(float f){
  unsigned u = __float_as_uint(f);
  return (u + 0x7FFFu + ((u >> 16) & 1u)) >> 16;  // RNE
}
__device__ __forceinline__ float gelu_t(float x){
  float x3 = x * x * x;
  return 0.5f * x * (1.f + tanhf(0.7978845608028654f * (x + 0.044715f * x3)));
}

// async global->LDS, 16B per lane. LDS dest = wave-uniform base + lane*16;
// global source address is PER-LANE (swizzle lives on the source side).
typedef const __attribute__((address_space(1))) unsigned int as1_uint;
typedef __attribute__((address_space(3))) unsigned int as3_uint;
__device__ __forceinline__ void gll16(const unsigned short* g, unsigned short* l) {
  __builtin_amdgcn_global_load_lds((as1_uint*)g, (as3_uint*)l, 16, 0, 0);
}

// ---------------- Router ----------------
__global__ __launch_bounds__(64) void router_kernel(
    const float* __restrict__ x, const float* __restrict__ gw,
    int* __restrict__ counts, int* __restrict__ list_ak, float* __restrict__ wlist)
{
  int t = blockIdx.x;
  int lane = threadIdx.x;
  float acc[NE];
  #pragma unroll
  for (int e = 0; e < NE; ++e) acc[e] = 0.f;
  const float* xr = x + (size_t)t * HD;
  #pragma unroll
  for (int j = 0; j < HD / 64; ++j) {
    int h = j * 64 + lane;
    float xv = xr[h];
    float4 g0 = *(const float4*)(gw + (size_t)h * NE);
    float4 g1 = *(const float4*)(gw + (size_t)h * NE + 4);
    acc[0] += xv * g0.x; acc[1] += xv * g0.y;
    acc[2] += xv * g0.z; acc[3] += xv * g0.w;
    acc[4] += xv * g1.x; acc[5] += xv * g1.y;
    acc[6] += xv * g1.z; acc[7] += xv * g1.w;
  }
  #pragma unroll
  for (int e = 0; e < NE; ++e) {
    float v = acc[e];
    #pragma unroll
    for (int off = 32; off > 0; off >>= 1) v += __shfl_xor(v, off, 64);
    acc[e] = v;
  }
  if (lane == 0) {
    float lg[NE];
    #pragma unroll
    for (int e = 0; e < NE; ++e) lg[e] = tanhf(acc[e] * (1.0f / 30.0f));
    int i0 = 0;
    #pragma unroll
    for (int e = 1; e < NE; ++e) if (lg[e] > lg[i0]) i0 = e;
    int i1 = (i0 == 0) ? 1 : 0;
    #pragma unroll
    for (int e = 0; e < NE; ++e) if (e != i0 && lg[e] > lg[i1]) i1 = e;
    float e1 = __expf(lg[i1] - lg[i0]);
    float w0 = 1.f / (1.f + e1);
    float w1 = 1.f - w0;
    int p0 = atomicAdd(counts + i0, 1);
    list_ak[i0 * TT + p0] = t * 2;
    wlist[i0 * TT + p0] = w0;
    int p1 = atomicAdd(counts + i1, 1);
    list_ak[i1 * TT + p1] = t * 2 + 1;
    wlist[i1 * TT + p1] = w1;
  }
}

// ---------------- x fp32 -> bf16 ----------------
__global__ void xcvt_kernel(const float* __restrict__ x, unsigned short* __restrict__ xb)
{
  int i = blockIdx.x * blockDim.x + threadIdx.x;   // 8 elems each
  const float* p = x + (size_t)i * 8;
  float4 v0 = *(const float4*)p;
  float4 v1 = *(const float4*)(p + 4);
  uint4 o;
  o.x = f2bf(v0.x) | (f2bf(v0.y) << 16);
  o.y = f2bf(v0.z) | (f2bf(v0.w) << 16);
  o.z = f2bf(v1.x) | (f2bf(v1.y) << 16);
  o.w = f2bf(v1.z) | (f2bf(v1.w) << 16);
  *(uint4*)(xb + (size_t)i * 8) = o;
}

// ---------------- weight transpose+convert: in fp32 [R][C] -> out bf16 [C][R]
__global__ __launch_bounds__(256) void tcvt_kernel(
    const float* __restrict__ in, unsigned short* __restrict__ out, int R, int C)
{
  __shared__ float tile[64 * 66];
  int e = blockIdx.z;
  const float* inp = in + (size_t)e * R * C;
  unsigned short* outp = out + (size_t)e * R * C;
  int r0 = blockIdx.y * 64, c0 = blockIdx.x * 64;
  int tid = threadIdx.x;
  int lr = tid >> 4, lc = (tid & 15) * 4;
  #pragma unroll
  for (int i = 0; i < 4; ++i) {
    float4 v = *(const float4*)(inp + (size_t)(r0 + i * 16 + lr) * C + c0 + lc);
    float* tp = &tile[(i * 16 + lr) * 66 + lc];
    tp[0] = v.x; tp[1] = v.y; tp[2] = v.z; tp[3] = v.w;
  }
  __syncthreads();
  int oc = tid >> 2, os = (tid & 3) * 16;
  unsigned short* op = outp + (size_t)(c0 + oc) * R + r0 + os;
  uint4 o[2];
  unsigned* ow = (unsigned*)o;
  #pragma unroll
  for (int m = 0; m < 8; ++m) {
    float a = tile[(os + 2 * m) * 66 + oc];
    float b = tile[(os + 2 * m + 1) * 66 + oc];
    ow[m] = f2bf(a) | (f2bf(b) << 16);
  }
  *(uint4*)op = o[0];
  *(uint4*)(op + 8) = o[1];
}

#define BK 32

// A LDS: linear [64 rows][32 k] bf16 (64B rows), staged by global_load_lds
// (per-lane gather on the GLOBAL side). 16B-unit XOR swizzle pre-applied to
// the global source k-chunk: stored unit u of row r holds chunk u^((r>>1)&3);
// frag reads apply the same XOR -> 2-way banks (free).
// B: NO LDS. Weights are pre-transposed bf16 -> each wave loads its own
// fragments straight to VGPRs (B frags are wave-private; the old LDS round
// trip was pure LDS-BW overhead). Same 64B-line coalescing.
// Grid (x=expert, y=m-slot, z=c): linear%8 == expert pins each expert to one
// XCD; the in-kernel m-loop makes all resident blocks of an XCD stream the
// same B panels concurrently -> re-reads are served by the XCD-private L2
// instead of Infinity Cache (the round-2 bottleneck).

// ---------------- Fused G+U gathered GEMM, act epilogue ----------------
__global__ __launch_bounds__(256, 4) void gu_gemm(
    const unsigned short* __restrict__ xb,   // [T,H] bf16
    const unsigned short* __restrict__ wgT,  // [E][I][H] bf16 (transposed)
    const unsigned short* __restrict__ wuT,
    unsigned short* __restrict__ act,        // [T*2, I] bf16
    const int* __restrict__ counts, const int* __restrict__ list_ak)
{
  int e = blockIdx.x;                 // XCD pin
  int nCnt = counts[e];
  int c0 = blockIdx.z * 128;
  const unsigned short* Wg = wgT + (size_t)e * HD * ID;
  const unsigned short* Wu = wuT + (size_t)e * HD * ID;

  __shared__ __align__(16) unsigned short As[2][64 * BK];   // 8 KB total

  int tid = threadIdx.x;
  int wave = tid >> 6, lane = tid & 63;
  int wn = wave * 32;
  int q = lane >> 4, l15 = lane & 15;
  int usw = ((lane & 3) ^ ((lane >> 3) & 3)) * 8;  // source k-chunk (shorts)
  int aldso = wave * 512;                          // wave stages 16 rows
  int afsw = (q ^ ((l15 >> 1) & 3)) * 8;           // frag-read swizzle

  // B per-lane bases: col = c0 + wn + nt*16 + l15, k = k0 + q*8
  const unsigned short* pBg = Wg + (size_t)(c0 + wn + l15) * HD + q * 8;
  const unsigned short* pBu = Wu + (size_t)(c0 + wn + l15) * HD + q * 8;
  const size_t ntstep = (size_t)16 * HD;

  for (int m0 = blockIdx.y * 64; m0 < nCnt; m0 += 8 * 64) {
    int gpos = m0 + wave * 16 + (lane >> 2);
    if (gpos >= nCnt) gpos = nCnt - 1;             // clamp, row unused
    const unsigned short* aptr =
        xb + (size_t)(list_ak[e * TT + gpos] >> 1) * HD + usw;

    f32x4 accg[4][2], accu[4][2];
    f32x4 zed = {0.f, 0.f, 0.f, 0.f};
    #pragma unroll
    for (int i = 0; i < 4; ++i)
      #pragma unroll
      for (int j = 0; j < 2; ++j) { accg[i][j] = zed; accu[i][j] = zed; }

    bf16x8 bgf[2], buf_[2];
    gll16(aptr, &As[0][aldso]);
    #pragma unroll
    for (int nt = 0; nt < 2; ++nt) {
      bgf[nt]  = *(const bf16x8*)(pBg + nt * ntstep);
      buf_[nt] = *(const bf16x8*)(pBu + nt * ntstep);
    }
    asm volatile("" ::: "memory");

    for (int k0 = 0; k0 < HD; k0 += BK) {
      int cur = (k0 >> 5) & 1;
      int nk = k0 + BK;
      if (nk < HD) {
        gll16(aptr + nk, &As[cur ^ 1][aldso]);
        asm volatile("s_waitcnt vmcnt(1)" ::: "memory");  // A(t)+B(t) done
      } else {
        asm volatile("s_waitcnt vmcnt(0)" ::: "memory");
      }
      __builtin_amdgcn_s_barrier();

      bf16x8 af[4];
      #pragma unroll
      for (int mt = 0; mt < 4; ++mt)
        af[mt] = *(const bf16x8*)(&As[cur][(mt * 16 + l15) * BK + afsw]);

      #pragma unroll
      for (int nt = 0; nt < 2; ++nt) {
        bf16x8 bg = bgf[nt], bu = buf_[nt];
        #pragma unroll
        for (int mt = 0; mt < 4; ++mt) {
          accg[mt][nt] = __builtin_amdgcn_mfma_f32_16x16x32_bf16(af[mt], bg, accg[mt][nt], 0, 0, 0);
          accu[mt][nt] = __builtin_amdgcn_mfma_f32_16x16x32_bf16(af[mt], bu, accu[mt][nt], 0, 0, 0);
        }
        if (nk < HD) {   // reload this nt's B frags for next tile
          bgf[nt]  = *(const bf16x8*)(pBg + nt * ntstep + nk);
          buf_[nt] = *(const bf16x8*)(pBu + nt * ntstep + nk);
        }
      }
      asm volatile("s_waitcnt lgkmcnt(0)" ::: "memory");
      asm volatile("" ::: "memory");
      __builtin_amdgcn_s_barrier();    // As[cur] reusable next iter
    }

    int cc = lane & 15, rg = lane >> 4;
    #pragma unroll
    for (int mt = 0; mt < 4; ++mt) {
      #pragma unroll
      for (int r = 0; r < 4; ++r) {
        int pos = m0 + mt * 16 + rg * 4 + r;
        if (pos >= nCnt) continue;
        int ak = list_ak[e * TT + pos];
        #pragma unroll
        for (int nt = 0; nt < 2; ++nt) {
          int ncol = c0 + wn + nt * 16 + cc;
          float avl = gelu_t(accg[mt][nt][r]) * accu[mt][nt][r];
          act[(size_t)ak * ID + ncol] = (unsigned short)f2bf(avl);
        }
      }
    }
  }
}

// ---------------- D GEMM: yw[ks] = w * (act @ WdT_e), split-K=2 ----------------
__global__ __launch_bounds__(256, 4) void d_gemm(
    const unsigned short* __restrict__ act,  // [T*2, I] bf16
    const unsigned short* __restrict__ wdT,  // [E][H][I] bf16 (transposed)
    float* __restrict__ yw,                  // [2][T*2, H] fp32 partials
    const int* __restrict__ counts, const int* __restrict__ list_ak,
    const float* __restrict__ wlist)
{
  int e = blockIdx.x;                 // XCD pin
  int nCnt = counts[e];
  int mslot = blockIdx.y >> 1;
  int ks = blockIdx.y & 1;
  int c0 = blockIdx.z * 128;
  const unsigned short* Wd = wdT + (size_t)e * ID * HD;   // [H][I]

  __shared__ __align__(16) unsigned short As[2][64 * BK];

  int tid = threadIdx.x;
  int wave = tid >> 6, lane = tid & 63;
  int wn = wave * 32;
  int q = lane >> 4, l15 = lane & 15;
  int usw = ((lane & 3) ^ ((lane >> 3) & 3)) * 8;
  int aldso = wave * 512;
  int afsw = (q ^ ((l15 >> 1) & 3)) * 8;

  const unsigned short* pB = Wd + (size_t)(c0 + wn + l15) * ID + ks * 1024 + q * 8;
  const size_t ntstep = (size_t)16 * ID;

  for (int m0 = mslot * 64; m0 < nCnt; m0 += 8 * 64) {
    int gpos = m0 + wave * 16 + (lane >> 2);
    if (gpos >= nCnt) gpos = nCnt - 1;
    const unsigned short* aptr =
        act + (size_t)list_ak[e * TT + gpos] * ID + ks * 1024 + usw;

    f32x4 acc[4][2];
    f32x4 zed = {0.f, 0.f, 0.f, 0.f};
    #pragma unroll
    for (int i = 0; i < 4; ++i)
      #pragma unroll
      for (int j = 0; j < 2; ++j) acc[i][j] = zed;

    bf16x8 bf[2];
    gll16(aptr, &As[0][aldso]);
    #pragma unroll
    for (int nt = 0; nt < 2; ++nt)
      bf[nt] = *(const bf16x8*)(pB + nt * ntstep);
    asm volatile("" ::: "memory");

    for (int k0 = 0; k0 < 1024; k0 += BK) {
      int cur = (k0 >> 5) & 1;
      int nk = k0 + BK;
      if (nk < 1024) {
        gll16(aptr + nk, &As[cur ^ 1][aldso]);
        asm volatile("s_waitcnt vmcnt(1)" ::: "memory");
      } else {
        asm volatile("s_waitcnt vmcnt(0)" ::: "memory");
      }
      __builtin_amdgcn_s_barrier();

      bf16x8 af[4];
      #pragma unroll
      for (int mt = 0; mt < 4; ++mt)
        af[mt] = *(const bf16x8*)(&As[cur][(mt * 16 + l15) * BK + afsw]);

      #pragma unroll
      for (int nt = 0; nt < 2; ++nt) {
        bf16x8 b = bf[nt];
        #pragma unroll
        for (int mt = 0; mt < 4; ++mt)
          acc[mt][nt] = __builtin_amdgcn_mfma_f32_16x16x32_bf16(af[mt], b, acc[mt][nt], 0, 0, 0);
        if (nk < 1024)
          bf[nt] = *(const bf16x8*)(pB + nt * ntstep + nk);
      }
      asm volatile("s_waitcnt lgkmcnt(0)" ::: "memory");
      asm volatile("" ::: "memory");
      __builtin_amdgcn_s_barrier();
    }

    int cc = lane & 15, rg = lane >> 4;
    #pragma unroll
    for (int mt = 0; mt < 4; ++mt) {
      #pragma unroll
      for (int r = 0; r < 4; ++r) {
        int pos = m0 + mt * 16 + rg * 4 + r;
        if (pos >= nCnt) continue;
        int ak = list_ak[e * TT + pos];
        float wsc = wlist[e * TT + pos];
        #pragma unroll
        for (int nt = 0; nt < 2; ++nt) {
          int ncol = c0 + wn + nt * 16 + cc;
          yw[((size_t)ks * (TT * 2) + ak) * HD + ncol] = acc[mt][nt][r] * wsc;
        }
      }
    }
  }
}

// ---------------- out[t,h] = sum over {2t,2t+1} x {ks0,ks1} ----------------
__global__ void combine_kernel(const float* __restrict__ yw, float* __restrict__ out)
{
  const int total = TT * HD / 4;
  const size_t S = (size_t)TT * 2 * HD;
  for (int i = blockIdx.x * blockDim.x + threadIdx.x; i < total;
       i += gridDim.x * blockDim.x) {
    int i4 = i * 4;
    int t = i4 >> 10;
    int h = i4 & (HD - 1);
    float4 a = *(const float4*)(yw + (size_t)(2 * t) * HD + h);
    float4 b = *(const float4*)(yw + (size_t)(2 * t + 1) * HD + h);
    float4 c = *(const float4*)(yw + S + (size_t)(2 * t) * HD + h);
    float4 d = *(const float4*)(yw + S + (size_t)(2 * t + 1) * HD + h);
    float4 o;
    o.x = a.x + b.x + c.x + d.x;
    o.y = a.y + b.y + c.y + d.y;
    o.z = a.z + b.z + c.z + d.z;
    o.w = a.w + b.w + c.w + d.w;
    *(float4*)(out + (size_t)i4) = o;
  }
}

extern "C" void kernel_launch(void* const* d_in, const int* in_sizes, int n_in,
                              void* d_out, int out_size, void* d_ws, size_t ws_size,
                              hipStream_t stream) {
  const float* x  = (const float*)d_in[0];
  const float* gw = (const float*)d_in[1];
  const float* wg = (const float*)d_in[2];
  const float* wu = (const float*)d_in[3];
  const float* wd = (const float*)d_in[4];
  float* out = (float*)d_out;

  // workspace layout (~156 MB total)
  char* ws = (char*)d_ws;
  int* counts   = (int*)ws;
  int* list_ak  = (int*)(ws + 256);
  float* wlist  = (float*)(ws + 256 + 65536);
  size_t off = 256 + 2 * 65536;
  unsigned short* xb  = (unsigned short*)(ws + off); off += (size_t)TT * HD * 2;        // 4 MB
  unsigned short* act = (unsigned short*)(ws + off); off += (size_t)TT * 2 * ID * 2;    // 16 MB
  float* yw           = (float*)(ws + off);          off += (size_t)2 * TT * 2 * HD * 4;// 33.5 MB
  unsigned short* wgT = (unsigned short*)(ws + off); off += (size_t)NE * HD * ID * 2;   // 33.5 MB
  unsigned short* wuT = (unsigned short*)(ws + off); off += (size_t)NE * HD * ID * 2;   // 33.5 MB
  unsigned short* wdT = (unsigned short*)(ws + off);                                    // 33.5 MB

  (void)hipMemsetAsync(counts, 0, 256, stream);
  router_kernel<<<TT, 64, 0, stream>>>(x, gw, counts, list_ak, wlist);
  xcvt_kernel<<<TT * HD / 8 / 256, 256, 0, stream>>>(x, xb);

  // weight convert+transpose: wg/wu [H][I] -> [I][H]; wd [I][H] -> [H][I]
  tcvt_kernel<<<dim3(ID / 64, HD / 64, NE), 256, 0, stream>>>(wg, wgT, HD, ID);
  tcvt_kernel<<<dim3(ID / 64, HD / 64, NE), 256, 0, stream>>>(wu, wuT, HD, ID);
  tcvt_kernel<<<dim3(HD / 64, ID / 64, NE), 256, 0, stream>>>(wd, wdT, ID, HD);

  dim3 blk(256);
  // grid.x = expert -> linear%8 == expert -> XCD-pinned; y = m-slot; z = c
  dim3 gGU(NE, 8, ID / 128);
  gu_gemm<<<gGU, blk, 0, stream>>>(xb, wgT, wuT, act, counts, list_ak);

  dim3 gD(NE, 16, HD / 128);   // y = 8 m-slots x 2 k-slices
  d_gemm<<<gD, blk, 0, stream>>>(act, wdT, yw, counts, list_ak, wlist);

  combine_kernel<<<1024, 256, 0, stream>>>(yw, out);
}

// Round 4
// 403.957 us; speedup vs baseline: 1.2183x; 1.2183x over previous
//
#include <hip/hip_runtime.h>
#include <hip/hip_bf16.h>

#define TT 2048
#define HD 1024
#define NE 8
#define ID 2048

typedef short bf16x8 __attribute__((ext_vector_type(8)));
typedef float f32x4 __attribute__((ext_vector_type(4)));

__device__ __forceinline__ unsigned f2bf(float f){
  unsigned u = __float_as_uint(f);
  return (u + 0x7FFFu + ((u >> 16) & 1u)) >> 16;  // RNE
}
__device__ __forceinline__ float gelu_t(float x){
  float x3 = x * x * x;
  return 0.5f * x * (1.f + tanhf(0.7978845608028654f * (x + 0.044715f * x3)));
}

// async global->LDS, 16B per lane. LDS dest = wave-uniform base + lane*16;
// global source address is PER-LANE (swizzle lives on the source side).
typedef const __attribute__((address_space(1))) unsigned int as1_uint;
typedef __attribute__((address_space(3))) unsigned int as3_uint;
__device__ __forceinline__ void gll16(const unsigned short* g, unsigned short* l) {
  __builtin_amdgcn_global_load_lds((as1_uint*)g, (as3_uint*)l, 16, 0, 0);
}

// ---------------- Router ----------------
__global__ __launch_bounds__(64) void router_kernel(
    const float* __restrict__ x, const float* __restrict__ gw,
    int* __restrict__ counts, int* __restrict__ list_ak, float* __restrict__ wlist)
{
  int t = blockIdx.x;
  int lane = threadIdx.x;
  float acc[NE];
  #pragma unroll
  for (int e = 0; e < NE; ++e) acc[e] = 0.f;
  const float* xr = x + (size_t)t * HD;
  #pragma unroll
  for (int j = 0; j < HD / 64; ++j) {
    int h = j * 64 + lane;
    float xv = xr[h];
    float4 g0 = *(const float4*)(gw + (size_t)h * NE);
    float4 g1 = *(const float4*)(gw + (size_t)h * NE + 4);
    acc[0] += xv * g0.x; acc[1] += xv * g0.y;
    acc[2] += xv * g0.z; acc[3] += xv * g0.w;
    acc[4] += xv * g1.x; acc[5] += xv * g1.y;
    acc[6] += xv * g1.z; acc[7] += xv * g1.w;
  }
  #pragma unroll
  for (int e = 0; e < NE; ++e) {
    float v = acc[e];
    #pragma unroll
    for (int off = 32; off > 0; off >>= 1) v += __shfl_xor(v, off, 64);
    acc[e] = v;
  }
  if (lane == 0) {
    float lg[NE];
    #pragma unroll
    for (int e = 0; e < NE; ++e) lg[e] = tanhf(acc[e] * (1.0f / 30.0f));
    int i0 = 0;
    #pragma unroll
    for (int e = 1; e < NE; ++e) if (lg[e] > lg[i0]) i0 = e;
    int i1 = (i0 == 0) ? 1 : 0;
    #pragma unroll
    for (int e = 0; e < NE; ++e) if (e != i0 && lg[e] > lg[i1]) i1 = e;
    float e1 = __expf(lg[i1] - lg[i0]);
    float w0 = 1.f / (1.f + e1);
    float w1 = 1.f - w0;
    int p0 = atomicAdd(counts + i0, 1);
    list_ak[i0 * TT + p0] = t * 2;
    wlist[i0 * TT + p0] = w0;
    int p1 = atomicAdd(counts + i1, 1);
    list_ak[i1 * TT + p1] = t * 2 + 1;
    wlist[i1 * TT + p1] = w1;
  }
}

// ---------------- x fp32 -> bf16 ----------------
__global__ void xcvt_kernel(const float* __restrict__ x, unsigned short* __restrict__ xb)
{
  int i = blockIdx.x * blockDim.x + threadIdx.x;   // 8 elems each
  const float* p = x + (size_t)i * 8;
  float4 v0 = *(const float4*)p;
  float4 v1 = *(const float4*)(p + 4);
  uint4 o;
  o.x = f2bf(v0.x) | (f2bf(v0.y) << 16);
  o.y = f2bf(v0.z) | (f2bf(v0.w) << 16);
  o.z = f2bf(v1.x) | (f2bf(v1.y) << 16);
  o.w = f2bf(v1.z) | (f2bf(v1.w) << 16);
  *(uint4*)(xb + (size_t)i * 8) = o;
}

// ---------------- weight transpose+convert: in fp32 [R][C] -> out bf16 [C][R]
__global__ __launch_bounds__(256) void tcvt_kernel(
    const float* __restrict__ in, unsigned short* __restrict__ out, int R, int C)
{
  __shared__ float tile[64 * 66];
  int e = blockIdx.z;
  const float* inp = in + (size_t)e * R * C;
  unsigned short* outp = out + (size_t)e * R * C;
  int r0 = blockIdx.y * 64, c0 = blockIdx.x * 64;
  int tid = threadIdx.x;
  int lr = tid >> 4, lc = (tid & 15) * 4;
  #pragma unroll
  for (int i = 0; i < 4; ++i) {
    float4 v = *(const float4*)(inp + (size_t)(r0 + i * 16 + lr) * C + c0 + lc);
    float* tp = &tile[(i * 16 + lr) * 66 + lc];
    tp[0] = v.x; tp[1] = v.y; tp[2] = v.z; tp[3] = v.w;
  }
  __syncthreads();
  int oc = tid >> 2, os = (tid & 3) * 16;
  unsigned short* op = outp + (size_t)(c0 + oc) * R + r0 + os;
  uint4 o[2];
  unsigned* ow = (unsigned*)o;
  #pragma unroll
  for (int m = 0; m < 8; ++m) {
    float a = tile[(os + 2 * m) * 66 + oc];
    float b = tile[(os + 2 * m + 1) * 66 + oc];
    ow[m] = f2bf(a) | (f2bf(b) << 16);
  }
  *(uint4*)op = o[0];
  *(uint4*)(op + 8) = o[1];
}

#define BK 32
#define BM 128

// LDS: linear [rows][32 k] bf16 (64B rows), staged entirely by global_load_lds
// (per-lane gather on the GLOBAL side). 16B-unit XOR swizzle pre-applied to the
// global source k-chunk: stored unit u of row r holds chunk u^((r>>1)&3); frag
// reads apply the same XOR -> conflict-free (measured 0).
// Counted-vmcnt pipeline: stage(t+1) at top of iter t; s_waitcnt vmcnt(N)
// drains ONLY tile t's N glls; loads get a full iteration of latency slack.
// Round-4 change: 128x128 tiles (was 64x128) -> B-panel re-reads halve; the
// round-2 counters showed ~8.2 TB/s of L2/L3 fabric traffic = the bottleneck.

// ---------------- Fused G+U gathered GEMM, act epilogue ----------------
__global__ __launch_bounds__(256, 2) void gu_gemm(
    const unsigned short* __restrict__ xb,   // [T,H] bf16
    const unsigned short* __restrict__ wgT,  // [E][I][H] bf16 (transposed)
    const unsigned short* __restrict__ wuT,
    unsigned short* __restrict__ act,        // [T*2, I] bf16
    const int* __restrict__ counts, const int* __restrict__ list_ak)
{
  int e = blockIdx.z;
  int nCnt = counts[e];
  int m0 = blockIdx.y * BM;
  if (m0 >= nCnt) return;
  int c0 = blockIdx.x * 128;
  const unsigned short* Wg = wgT + (size_t)e * HD * ID;
  const unsigned short* Wu = wuT + (size_t)e * HD * ID;

  __shared__ __align__(16) unsigned short As[2][BM * BK];    // 16 KB
  __shared__ __align__(16) unsigned short Bg[2][128 * BK];   // 16 KB
  __shared__ __align__(16) unsigned short Bu[2][128 * BK];   // 16 KB

  int tid = threadIdx.x;
  int wave = tid >> 6, lane = tid & 63;
  int wn = wave * 32;
  int q = lane >> 4, l15 = lane & 15;
  int usw = ((lane & 3) ^ ((lane >> 3) & 3)) * 8;  // source k-chunk (shorts)
  int fsw = (q ^ ((l15 >> 1) & 3)) * 8;            // frag-read swizzle

  // A rows: two 64-row halves; wave stages 16 rows per half
  int r1 = wave * 16 + (lane >> 2);
  int g1p = m0 + r1;       if (g1p >= nCnt) g1p = nCnt - 1;
  int g2p = m0 + 64 + r1;  if (g2p >= nCnt) g2p = nCnt - 1;
  const unsigned short* aptr1 =
      xb + (size_t)(list_ak[e * TT + g1p] >> 1) * HD + usw;
  const unsigned short* aptr2 =
      xb + (size_t)(list_ak[e * TT + g2p] >> 1) * HD + usw;
  int aldso = wave * 512;          // shorts

  // B: lane -> col wave*16+(lane>>2) (+64 via bstep), same source swizzle
  int colL = wave * 16 + (lane >> 2);
  const unsigned short* bg0 = Wg + (size_t)(c0 + colL) * HD + usw;
  const unsigned short* bu0 = Wu + (size_t)(c0 + colL) * HD + usw;
  const size_t bstep = (size_t)64 * HD;
  int ldso = wave * 512;

  // 6 glls per tile
  auto stage = [&](int k0, int b) {
    gll16(aptr1 + k0,        &As[b][aldso]);
    gll16(aptr2 + k0,        &As[b][2048 + aldso]);
    gll16(bg0 + k0,          &Bg[b][ldso]);
    gll16(bg0 + k0 + bstep,  &Bg[b][2048 + ldso]);
    gll16(bu0 + k0,          &Bu[b][ldso]);
    gll16(bu0 + k0 + bstep,  &Bu[b][2048 + ldso]);
  };

  f32x4 accg[8][2], accu[8][2];
  f32x4 zed = {0.f, 0.f, 0.f, 0.f};
  #pragma unroll
  for (int i = 0; i < 8; ++i)
    #pragma unroll
    for (int j = 0; j < 2; ++j) { accg[i][j] = zed; accu[i][j] = zed; }

  stage(0, 0);

  for (int k0 = 0; k0 < HD; k0 += BK) {
    int cur = (k0 >> 5) & 1;
    if (k0 + BK < HD) {
      stage(k0 + BK, cur ^ 1);
      asm volatile("s_waitcnt vmcnt(6)" ::: "memory");  // drain tile t only
    } else {
      asm volatile("s_waitcnt vmcnt(0)" ::: "memory");
    }
    __builtin_amdgcn_s_barrier();

    bf16x8 af[8];
    #pragma unroll
    for (int mt = 0; mt < 8; ++mt)
      af[mt] = *(const bf16x8*)(&As[cur][(mt * 16 + l15) * BK + fsw]);
    #pragma unroll
    for (int nt = 0; nt < 2; ++nt) {
      int col = wn + nt * 16 + l15;
      bf16x8 bgf  = *(const bf16x8*)(&Bg[cur][col * BK + fsw]);
      bf16x8 buf_ = *(const bf16x8*)(&Bu[cur][col * BK + fsw]);
      #pragma unroll
      for (int mt = 0; mt < 8; ++mt) {
        accg[mt][nt] = __builtin_amdgcn_mfma_f32_16x16x32_bf16(af[mt], bgf,  accg[mt][nt], 0, 0, 0);
        accu[mt][nt] = __builtin_amdgcn_mfma_f32_16x16x32_bf16(af[mt], buf_, accu[mt][nt], 0, 0, 0);
      }
    }
    asm volatile("s_waitcnt lgkmcnt(0)" ::: "memory");  // frag reads done
    __builtin_amdgcn_s_barrier();                       // buf cur reusable
  }

  int cc = lane & 15, rg = lane >> 4;
  #pragma unroll
  for (int mt = 0; mt < 8; ++mt) {
    #pragma unroll
    for (int r = 0; r < 4; ++r) {
      int pos = m0 + mt * 16 + rg * 4 + r;
      if (pos >= nCnt) continue;
      int ak = list_ak[e * TT + pos];
      #pragma unroll
      for (int nt = 0; nt < 2; ++nt) {
        int ncol = c0 + wn + nt * 16 + cc;
        float avl = gelu_t(accg[mt][nt][r]) * accu[mt][nt][r];
        act[(size_t)ak * ID + ncol] = (unsigned short)f2bf(avl);
      }
    }
  }
}

// ---------------- D GEMM: yw[ks] = w * (act @ WdT_e), split-K=2 ----------------
__global__ __launch_bounds__(256, 3) void d_gemm(
    const unsigned short* __restrict__ act,  // [T*2, I] bf16
    const unsigned short* __restrict__ wdT,  // [E][H][I] bf16 (transposed)
    float* __restrict__ yw,                  // [2][T*2, H] fp32 partials
    const int* __restrict__ counts, const int* __restrict__ list_ak,
    const float* __restrict__ wlist)
{
  int e = blockIdx.z;
  int nCnt = counts[e];
  int m0 = (blockIdx.y >> 1) * BM;
  int ks = blockIdx.y & 1;
  if (m0 >= nCnt) return;
  int c0 = blockIdx.x * 128;
  const unsigned short* Wd = wdT + (size_t)e * ID * HD;   // [H][I]

  __shared__ __align__(16) unsigned short As[2][BM * BK];    // 16 KB
  __shared__ __align__(16) unsigned short Bt[2][128 * BK];   // 16 KB

  int tid = threadIdx.x;
  int wave = tid >> 6, lane = tid & 63;
  int wn = wave * 32;
  int q = lane >> 4, l15 = lane & 15;
  int usw = ((lane & 3) ^ ((lane >> 3) & 3)) * 8;
  int fsw = (q ^ ((l15 >> 1) & 3)) * 8;

  int r1 = wave * 16 + (lane >> 2);
  int g1p = m0 + r1;       if (g1p >= nCnt) g1p = nCnt - 1;
  int g2p = m0 + 64 + r1;  if (g2p >= nCnt) g2p = nCnt - 1;
  const unsigned short* aptr1 =
      act + (size_t)list_ak[e * TT + g1p] * ID + ks * 1024 + usw;
  const unsigned short* aptr2 =
      act + (size_t)list_ak[e * TT + g2p] * ID + ks * 1024 + usw;
  int aldso = wave * 512;

  int colL = wave * 16 + (lane >> 2);
  const unsigned short* bp0 = Wd + (size_t)(c0 + colL) * ID + ks * 1024 + usw;
  const size_t bstep = (size_t)64 * ID;
  int ldso = wave * 512;

  // 4 glls per tile
  auto stage = [&](int k0, int b) {
    gll16(aptr1 + k0,       &As[b][aldso]);
    gll16(aptr2 + k0,       &As[b][2048 + aldso]);
    gll16(bp0 + k0,         &Bt[b][ldso]);
    gll16(bp0 + k0 + bstep, &Bt[b][2048 + ldso]);
  };

  f32x4 acc[8][2];
  f32x4 zed = {0.f, 0.f, 0.f, 0.f};
  #pragma unroll
  for (int i = 0; i < 8; ++i)
    #pragma unroll
    for (int j = 0; j < 2; ++j) acc[i][j] = zed;

  stage(0, 0);

  for (int k0 = 0; k0 < 1024; k0 += BK) {
    int cur = (k0 >> 5) & 1;
    if (k0 + BK < 1024) {
      stage(k0 + BK, cur ^ 1);
      asm volatile("s_waitcnt vmcnt(4)" ::: "memory");
    } else {
      asm volatile("s_waitcnt vmcnt(0)" ::: "memory");
    }
    __builtin_amdgcn_s_barrier();

    bf16x8 af[8], bf[2];
    #pragma unroll
    for (int mt = 0; mt < 8; ++mt)
      af[mt] = *(const bf16x8*)(&As[cur][(mt * 16 + l15) * BK + fsw]);
    #pragma unroll
    for (int nt = 0; nt < 2; ++nt) {
      int col = wn + nt * 16 + l15;
      bf[nt] = *(const bf16x8*)(&Bt[cur][col * BK + fsw]);
    }
    #pragma unroll
    for (int mt = 0; mt < 8; ++mt)
      #pragma unroll
      for (int nt = 0; nt < 2; ++nt)
        acc[mt][nt] = __builtin_amdgcn_mfma_f32_16x16x32_bf16(af[mt], bf[nt], acc[mt][nt], 0, 0, 0);

    asm volatile("s_waitcnt lgkmcnt(0)" ::: "memory");
    __builtin_amdgcn_s_barrier();
  }

  int cc = lane & 15, rg = lane >> 4;
  #pragma unroll
  for (int mt = 0; mt < 8; ++mt) {
    #pragma unroll
    for (int r = 0; r < 4; ++r) {
      int pos = m0 + mt * 16 + rg * 4 + r;
      if (pos >= nCnt) continue;
      int ak = list_ak[e * TT + pos];
      float wsc = wlist[e * TT + pos];
      #pragma unroll
      for (int nt = 0; nt < 2; ++nt) {
        int ncol = c0 + wn + nt * 16 + cc;
        yw[((size_t)ks * (TT * 2) + ak) * HD + ncol] = acc[mt][nt][r] * wsc;
      }
    }
  }
}

// ---------------- out[t,h] = sum over {2t,2t+1} x {ks0,ks1} ----------------
__global__ void combine_kernel(const float* __restrict__ yw, float* __restrict__ out)
{
  const int total = TT * HD / 4;
  const size_t S = (size_t)TT * 2 * HD;
  for (int i = blockIdx.x * blockDim.x + threadIdx.x; i < total;
       i += gridDim.x * blockDim.x) {
    int i4 = i * 4;
    int t = i4 >> 10;
    int h = i4 & (HD - 1);
    float4 a = *(const float4*)(yw + (size_t)(2 * t) * HD + h);
    float4 b = *(const float4*)(yw + (size_t)(2 * t + 1) * HD + h);
    float4 c = *(const float4*)(yw + S + (size_t)(2 * t) * HD + h);
    float4 d = *(const float4*)(yw + S + (size_t)(2 * t + 1) * HD + h);
    float4 o;
    o.x = a.x + b.x + c.x + d.x;
    o.y = a.y + b.y + c.y + d.y;
    o.z = a.z + b.z + c.z + d.z;
    o.w = a.w + b.w + c.w + d.w;
    *(float4*)(out + (size_t)i4) = o;
  }
}

extern "C" void kernel_launch(void* const* d_in, const int* in_sizes, int n_in,
                              void* d_out, int out_size, void* d_ws, size_t ws_size,
                              hipStream_t stream) {
  const float* x  = (const float*)d_in[0];
  const float* gw = (const float*)d_in[1];
  const float* wg = (const float*)d_in[2];
  const float* wu = (const float*)d_in[3];
  const float* wd = (const float*)d_in[4];
  float* out = (float*)d_out;

  // workspace layout (~156 MB total)
  char* ws = (char*)d_ws;
  int* counts   = (int*)ws;
  int* list_ak  = (int*)(ws + 256);
  float* wlist  = (float*)(ws + 256 + 65536);
  size_t off = 256 + 2 * 65536;
  unsigned short* xb  = (unsigned short*)(ws + off); off += (size_t)TT * HD * 2;        // 4 MB
  unsigned short* act = (unsigned short*)(ws + off); off += (size_t)TT * 2 * ID * 2;    // 16 MB
  float* yw           = (float*)(ws + off);          off += (size_t)2 * TT * 2 * HD * 4;// 33.5 MB
  unsigned short* wgT = (unsigned short*)(ws + off); off += (size_t)NE * HD * ID * 2;   // 33.5 MB
  unsigned short* wuT = (unsigned short*)(ws + off); off += (size_t)NE * HD * ID * 2;   // 33.5 MB
  unsigned short* wdT = (unsigned short*)(ws + off);                                    // 33.5 MB

  (void)hipMemsetAsync(counts, 0, 256, stream);
  router_kernel<<<TT, 64, 0, stream>>>(x, gw, counts, list_ak, wlist);
  xcvt_kernel<<<TT * HD / 8 / 256, 256, 0, stream>>>(x, xb);

  // weight convert+transpose: wg/wu [H][I] -> [I][H]; wd [I][H] -> [H][I]
  tcvt_kernel<<<dim3(ID / 64, HD / 64, NE), 256, 0, stream>>>(wg, wgT, HD, ID);
  tcvt_kernel<<<dim3(ID / 64, HD / 64, NE), 256, 0, stream>>>(wu, wuT, HD, ID);
  tcvt_kernel<<<dim3(HD / 64, ID / 64, NE), 256, 0, stream>>>(wd, wdT, ID, HD);

  dim3 blk(256);
  dim3 gGU(ID / 128, 16, NE);    // 16 m-slots x 128 rows covers nCnt<=2048
  gu_gemm<<<gGU, blk, 0, stream>>>(xb, wgT, wuT, act, counts, list_ak);

  dim3 gD(HD / 128, 32, NE);     // y = 16 m-slots x 2 k-slices
  d_gemm<<<gD, blk, 0, stream>>>(act, wdT, yw, counts, list_ak, wlist);

  combine_kernel<<<1024, 256, 0, stream>>>(yw, out);
}

// Round 5
// 381.127 us; speedup vs baseline: 1.2913x; 1.0599x over previous
//
#include <hip/hip_runtime.h>
#include <hip/hip_bf16.h>

#define TT 2048
#define HD 1024
#define NE 8
#define ID 2048

typedef short bf16x8 __attribute__((ext_vector_type(8)));
typedef float f32x4 __attribute__((ext_vector_type(4)));

__device__ __forceinline__ unsigned f2bf(float f){
  unsigned u = __float_as_uint(f);
  return (u + 0x7FFFu + ((u >> 16) & 1u)) >> 16;  // RNE
}
__device__ __forceinline__ float gelu_t(float x){
  float x3 = x * x * x;
  return 0.5f * x * (1.f + tanhf(0.7978845608028654f * (x + 0.044715f * x3)));
}

// async global->LDS, 16B per lane. LDS dest = wave-uniform base + lane*16;
// global source address is PER-LANE (swizzle lives on the source side).
typedef const __attribute__((address_space(1))) unsigned int as1_uint;
typedef __attribute__((address_space(3))) unsigned int as3_uint;
__device__ __forceinline__ void gll16(const unsigned short* g, unsigned short* l) {
  __builtin_amdgcn_global_load_lds((as1_uint*)g, (as3_uint*)l, 16, 0, 0);
}

// ---------------- Router ----------------
__global__ __launch_bounds__(64) void router_kernel(
    const float* __restrict__ x, const float* __restrict__ gw,
    int* __restrict__ counts, int* __restrict__ list_ak, float* __restrict__ wlist)
{
  int t = blockIdx.x;
  int lane = threadIdx.x;
  float acc[NE];
  #pragma unroll
  for (int e = 0; e < NE; ++e) acc[e] = 0.f;
  const float* xr = x + (size_t)t * HD;
  #pragma unroll
  for (int j = 0; j < HD / 64; ++j) {
    int h = j * 64 + lane;
    float xv = xr[h];
    float4 g0 = *(const float4*)(gw + (size_t)h * NE);
    float4 g1 = *(const float4*)(gw + (size_t)h * NE + 4);
    acc[0] += xv * g0.x; acc[1] += xv * g0.y;
    acc[2] += xv * g0.z; acc[3] += xv * g0.w;
    acc[4] += xv * g1.x; acc[5] += xv * g1.y;
    acc[6] += xv * g1.z; acc[7] += xv * g1.w;
  }
  #pragma unroll
  for (int e = 0; e < NE; ++e) {
    float v = acc[e];
    #pragma unroll
    for (int off = 32; off > 0; off >>= 1) v += __shfl_xor(v, off, 64);
    acc[e] = v;
  }
  if (lane == 0) {
    float lg[NE];
    #pragma unroll
    for (int e = 0; e < NE; ++e) lg[e] = tanhf(acc[e] * (1.0f / 30.0f));
    int i0 = 0;
    #pragma unroll
    for (int e = 1; e < NE; ++e) if (lg[e] > lg[i0]) i0 = e;
    int i1 = (i0 == 0) ? 1 : 0;
    #pragma unroll
    for (int e = 0; e < NE; ++e) if (e != i0 && lg[e] > lg[i1]) i1 = e;
    float e1 = __expf(lg[i1] - lg[i0]);
    float w0 = 1.f / (1.f + e1);
    float w1 = 1.f - w0;
    int p0 = atomicAdd(counts + i0, 1);
    list_ak[i0 * TT + p0] = t * 2;
    wlist[i0 * TT + p0] = w0;
    int p1 = atomicAdd(counts + i1, 1);
    list_ak[i1 * TT + p1] = t * 2 + 1;
    wlist[i1 * TT + p1] = w1;
  }
}

// ---------------- x fp32 -> bf16 ----------------
__global__ void xcvt_kernel(const float* __restrict__ x, unsigned short* __restrict__ xb)
{
  int i = blockIdx.x * blockDim.x + threadIdx.x;   // 8 elems each
  const float* p = x + (size_t)i * 8;
  float4 v0 = *(const float4*)p;
  float4 v1 = *(const float4*)(p + 4);
  uint4 o;
  o.x = f2bf(v0.x) | (f2bf(v0.y) << 16);
  o.y = f2bf(v0.z) | (f2bf(v0.w) << 16);
  o.z = f2bf(v1.x) | (f2bf(v1.y) << 16);
  o.w = f2bf(v1.z) | (f2bf(v1.w) << 16);
  *(uint4*)(xb + (size_t)i * 8) = o;
}

// ---------------- weight transpose+convert: in fp32 [R][C] -> out bf16 [C][R]
__global__ __launch_bounds__(256) void tcvt_kernel(
    const float* __restrict__ in, unsigned short* __restrict__ out, int R, int C)
{
  __shared__ float tile[64 * 66];
  int e = blockIdx.z;
  const float* inp = in + (size_t)e * R * C;
  unsigned short* outp = out + (size_t)e * R * C;
  int r0 = blockIdx.y * 64, c0 = blockIdx.x * 64;
  int tid = threadIdx.x;
  int lr = tid >> 4, lc = (tid & 15) * 4;
  #pragma unroll
  for (int i = 0; i < 4; ++i) {
    float4 v = *(const float4*)(inp + (size_t)(r0 + i * 16 + lr) * C + c0 + lc);
    float* tp = &tile[(i * 16 + lr) * 66 + lc];
    tp[0] = v.x; tp[1] = v.y; tp[2] = v.z; tp[3] = v.w;
  }
  __syncthreads();
  int oc = tid >> 2, os = (tid & 3) * 16;
  unsigned short* op = outp + (size_t)(c0 + oc) * R + r0 + os;
  uint4 o[2];
  unsigned* ow = (unsigned*)o;
  #pragma unroll
  for (int m = 0; m < 8; ++m) {
    float a = tile[(os + 2 * m) * 66 + oc];
    float b = tile[(os + 2 * m + 1) * 66 + oc];
    ow[m] = f2bf(a) | (f2bf(b) << 16);
  }
  *(uint4*)op = o[0];
  *(uint4*)(op + 8) = o[1];
}

#define BK 32
#define BM 128

// LDS: linear [rows][32 k] bf16 (64B rows), staged entirely by global_load_lds
// (per-lane gather on the GLOBAL side). 16B-unit XOR swizzle pre-applied to the
// global source k-chunk: stored unit u of row r holds chunk u^((r>>1)&3); frag
// reads apply the same XOR -> conflict-free (measured 0).
// Counted-vmcnt pipeline: stage(t+1) at top of iter t; s_waitcnt vmcnt(N)
// drains ONLY tile t's N glls; loads get a full iteration of latency slack.
// Round-5: 128x128 tiles (R4's halved traffic) + 512-thread/8-wave blocks ->
// 16 waves/CU (R2's TLP). R4 showed 2 blocks x 4 waves starves the fabric.

// ---------------- Fused G+U gathered GEMM, act epilogue ----------------
// 8 waves as 2m x 4n: wave computes 64m x 32n of both G and U.
__global__ __launch_bounds__(512, 4) void gu_gemm(
    const unsigned short* __restrict__ xb,   // [T,H] bf16
    const unsigned short* __restrict__ wgT,  // [E][I][H] bf16 (transposed)
    const unsigned short* __restrict__ wuT,
    unsigned short* __restrict__ act,        // [T*2, I] bf16
    const int* __restrict__ counts, const int* __restrict__ list_ak)
{
  int e = blockIdx.z;
  int nCnt = counts[e];
  int m0 = blockIdx.y * BM;
  if (m0 >= nCnt) return;
  int c0 = blockIdx.x * 128;
  const unsigned short* Wg = wgT + (size_t)e * HD * ID;
  const unsigned short* Wu = wuT + (size_t)e * HD * ID;

  __shared__ __align__(16) unsigned short As[2][BM * BK];    // 16 KB
  __shared__ __align__(16) unsigned short Bg[2][128 * BK];   // 16 KB
  __shared__ __align__(16) unsigned short Bu[2][128 * BK];   // 16 KB

  int tid = threadIdx.x;
  int wave = tid >> 6, lane = tid & 63;      // 8 waves
  int wm = wave >> 2, wnq = wave & 3;        // 2m x 4n
  int q = lane >> 4, l15 = lane & 15;
  int usw = ((lane & 3) ^ ((lane >> 3) & 3)) * 8;  // source k-chunk (shorts)
  int fsw = (q ^ ((l15 >> 1) & 3)) * 8;            // frag-read swizzle

  // staging: wave w covers rows/cols w*16 .. w*16+15 (lane>>2), unit lane&3
  int srow = wave * 16 + (lane >> 2);
  int gpos = m0 + srow; if (gpos >= nCnt) gpos = nCnt - 1;   // clamp, row unused
  const unsigned short* aptr =
      xb + (size_t)(list_ak[e * TT + gpos] >> 1) * HD + usw;
  const unsigned short* bgp = Wg + (size_t)(c0 + srow) * HD + usw;
  const unsigned short* bup = Wu + (size_t)(c0 + srow) * HD + usw;
  int so = wave * 512;   // shorts: wave-uniform LDS base (16 rows * 32)

  // 3 glls per wave per tile
  auto stage = [&](int k0, int b) {
    gll16(aptr + k0, &As[b][so]);
    gll16(bgp + k0,  &Bg[b][so]);
    gll16(bup + k0,  &Bu[b][so]);
  };

  f32x4 accg[4][2], accu[4][2];
  f32x4 zed = {0.f, 0.f, 0.f, 0.f};
  #pragma unroll
  for (int i = 0; i < 4; ++i)
    #pragma unroll
    for (int j = 0; j < 2; ++j) { accg[i][j] = zed; accu[i][j] = zed; }

  stage(0, 0);

  for (int k0 = 0; k0 < HD; k0 += BK) {
    int cur = (k0 >> 5) & 1;
    if (k0 + BK < HD) {
      stage(k0 + BK, cur ^ 1);
      asm volatile("s_waitcnt vmcnt(3)" ::: "memory");  // drain tile t only
    } else {
      asm volatile("s_waitcnt vmcnt(0)" ::: "memory");
    }
    __builtin_amdgcn_s_barrier();

    bf16x8 af[4];
    #pragma unroll
    for (int mt = 0; mt < 4; ++mt)
      af[mt] = *(const bf16x8*)(&As[cur][(wm * 64 + mt * 16 + l15) * BK + fsw]);
    #pragma unroll
    for (int nt = 0; nt < 2; ++nt) {
      int col = wnq * 32 + nt * 16 + l15;
      bf16x8 bgf  = *(const bf16x8*)(&Bg[cur][col * BK + fsw]);
      bf16x8 buf_ = *(const bf16x8*)(&Bu[cur][col * BK + fsw]);
      #pragma unroll
      for (int mt = 0; mt < 4; ++mt) {
        accg[mt][nt] = __builtin_amdgcn_mfma_f32_16x16x32_bf16(af[mt], bgf,  accg[mt][nt], 0, 0, 0);
        accu[mt][nt] = __builtin_amdgcn_mfma_f32_16x16x32_bf16(af[mt], buf_, accu[mt][nt], 0, 0, 0);
      }
    }
    asm volatile("s_waitcnt lgkmcnt(0)" ::: "memory");  // frag reads done
    __builtin_amdgcn_s_barrier();                       // buf cur reusable
  }

  int cc = l15, rg = q;
  #pragma unroll
  for (int mt = 0; mt < 4; ++mt) {
    #pragma unroll
    for (int r = 0; r < 4; ++r) {
      int pos = m0 + wm * 64 + mt * 16 + rg * 4 + r;
      if (pos >= nCnt) continue;
      int ak = list_ak[e * TT + pos];
      #pragma unroll
      for (int nt = 0; nt < 2; ++nt) {
        int ncol = c0 + wnq * 32 + nt * 16 + cc;
        float avl = gelu_t(accg[mt][nt][r]) * accu[mt][nt][r];
        act[(size_t)ak * ID + ncol] = (unsigned short)f2bf(avl);
      }
    }
  }
}

// ---------------- D GEMM: yw[ks] = w * (act @ WdT_e), split-K=2 ----------------
__global__ __launch_bounds__(512, 4) void d_gemm(
    const unsigned short* __restrict__ act,  // [T*2, I] bf16
    const unsigned short* __restrict__ wdT,  // [E][H][I] bf16 (transposed)
    float* __restrict__ yw,                  // [2][T*2, H] fp32 partials
    const int* __restrict__ counts, const int* __restrict__ list_ak,
    const float* __restrict__ wlist)
{
  int e = blockIdx.z;
  int nCnt = counts[e];
  int m0 = (blockIdx.y >> 1) * BM;
  int ks = blockIdx.y & 1;
  if (m0 >= nCnt) return;
  int c0 = blockIdx.x * 128;
  const unsigned short* Wd = wdT + (size_t)e * ID * HD;   // [H][I]

  __shared__ __align__(16) unsigned short As[2][BM * BK];    // 16 KB
  __shared__ __align__(16) unsigned short Bt[2][128 * BK];   // 16 KB

  int tid = threadIdx.x;
  int wave = tid >> 6, lane = tid & 63;
  int wm = wave >> 2, wnq = wave & 3;
  int q = lane >> 4, l15 = lane & 15;
  int usw = ((lane & 3) ^ ((lane >> 3) & 3)) * 8;
  int fsw = (q ^ ((l15 >> 1) & 3)) * 8;

  int srow = wave * 16 + (lane >> 2);
  int gpos = m0 + srow; if (gpos >= nCnt) gpos = nCnt - 1;
  const unsigned short* aptr =
      act + (size_t)list_ak[e * TT + gpos] * ID + ks * 1024 + usw;
  const unsigned short* bp =
      Wd + (size_t)(c0 + srow) * ID + ks * 1024 + usw;
  int so = wave * 512;

  // 2 glls per wave per tile
  auto stage = [&](int k0, int b) {
    gll16(aptr + k0, &As[b][so]);
    gll16(bp + k0,   &Bt[b][so]);
  };

  f32x4 acc[4][2];
  f32x4 zed = {0.f, 0.f, 0.f, 0.f};
  #pragma unroll
  for (int i = 0; i < 4; ++i)
    #pragma unroll
    for (int j = 0; j < 2; ++j) acc[i][j] = zed;

  stage(0, 0);

  for (int k0 = 0; k0 < 1024; k0 += BK) {
    int cur = (k0 >> 5) & 1;
    if (k0 + BK < 1024) {
      stage(k0 + BK, cur ^ 1);
      asm volatile("s_waitcnt vmcnt(2)" ::: "memory");
    } else {
      asm volatile("s_waitcnt vmcnt(0)" ::: "memory");
    }
    __builtin_amdgcn_s_barrier();

    bf16x8 af[4], bf[2];
    #pragma unroll
    for (int mt = 0; mt < 4; ++mt)
      af[mt] = *(const bf16x8*)(&As[cur][(wm * 64 + mt * 16 + l15) * BK + fsw]);
    #pragma unroll
    for (int nt = 0; nt < 2; ++nt) {
      int col = wnq * 32 + nt * 16 + l15;
      bf[nt] = *(const bf16x8*)(&Bt[cur][col * BK + fsw]);
    }
    #pragma unroll
    for (int mt = 0; mt < 4; ++mt)
      #pragma unroll
      for (int nt = 0; nt < 2; ++nt)
        acc[mt][nt] = __builtin_amdgcn_mfma_f32_16x16x32_bf16(af[mt], bf[nt], acc[mt][nt], 0, 0, 0);

    asm volatile("s_waitcnt lgkmcnt(0)" ::: "memory");
    __builtin_amdgcn_s_barrier();
  }

  int cc = l15, rg = q;
  #pragma unroll
  for (int mt = 0; mt < 4; ++mt) {
    #pragma unroll
    for (int r = 0; r < 4; ++r) {
      int pos = m0 + wm * 64 + mt * 16 + rg * 4 + r;
      if (pos >= nCnt) continue;
      int ak = list_ak[e * TT + pos];
      float wsc = wlist[e * TT + pos];
      #pragma unroll
      for (int nt = 0; nt < 2; ++nt) {
        int ncol = c0 + wnq * 32 + nt * 16 + cc;
        yw[((size_t)ks * (TT * 2) + ak) * HD + ncol] = acc[mt][nt][r] * wsc;
      }
    }
  }
}

// ---------------- out[t,h] = sum over {2t,2t+1} x {ks0,ks1} ----------------
__global__ void combine_kernel(const float* __restrict__ yw, float* __restrict__ out)
{
  const int total = TT * HD / 4;
  const size_t S = (size_t)TT * 2 * HD;
  for (int i = blockIdx.x * blockDim.x + threadIdx.x; i < total;
       i += gridDim.x * blockDim.x) {
    int i4 = i * 4;
    int t = i4 >> 10;
    int h = i4 & (HD - 1);
    float4 a = *(const float4*)(yw + (size_t)(2 * t) * HD + h);
    float4 b = *(const float4*)(yw + (size_t)(2 * t + 1) * HD + h);
    float4 c = *(const float4*)(yw + S + (size_t)(2 * t) * HD + h);
    float4 d = *(const float4*)(yw + S + (size_t)(2 * t + 1) * HD + h);
    float4 o;
    o.x = a.x + b.x + c.x + d.x;
    o.y = a.y + b.y + c.y + d.y;
    o.z = a.z + b.z + c.z + d.z;
    o.w = a.w + b.w + c.w + d.w;
    *(float4*)(out + (size_t)i4) = o;
  }
}

extern "C" void kernel_launch(void* const* d_in, const int* in_sizes, int n_in,
                              void* d_out, int out_size, void* d_ws, size_t ws_size,
                              hipStream_t stream) {
  const float* x  = (const float*)d_in[0];
  const float* gw = (const float*)d_in[1];
  const float* wg = (const float*)d_in[2];
  const float* wu = (const float*)d_in[3];
  const float* wd = (const float*)d_in[4];
  float* out = (float*)d_out;

  // workspace layout (~156 MB total)
  char* ws = (char*)d_ws;
  int* counts   = (int*)ws;
  int* list_ak  = (int*)(ws + 256);
  float* wlist  = (float*)(ws + 256 + 65536);
  size_t off = 256 + 2 * 65536;
  unsigned short* xb  = (unsigned short*)(ws + off); off += (size_t)TT * HD * 2;        // 4 MB
  unsigned short* act = (unsigned short*)(ws + off); off += (size_t)TT * 2 * ID * 2;    // 16 MB
  float* yw           = (float*)(ws + off);          off += (size_t)2 * TT * 2 * HD * 4;// 33.5 MB
  unsigned short* wgT = (unsigned short*)(ws + off); off += (size_t)NE * HD * ID * 2;   // 33.5 MB
  unsigned short* wuT = (unsigned short*)(ws + off); off += (size_t)NE * HD * ID * 2;   // 33.5 MB
  unsigned short* wdT = (unsigned short*)(ws + off);                                    // 33.5 MB

  (void)hipMemsetAsync(counts, 0, 256, stream);
  router_kernel<<<TT, 64, 0, stream>>>(x, gw, counts, list_ak, wlist);
  xcvt_kernel<<<TT * HD / 8 / 256, 256, 0, stream>>>(x, xb);

  // weight convert+transpose: wg/wu [H][I] -> [I][H]; wd [I][H] -> [H][I]
  tcvt_kernel<<<dim3(ID / 64, HD / 64, NE), 256, 0, stream>>>(wg, wgT, HD, ID);
  tcvt_kernel<<<dim3(ID / 64, HD / 64, NE), 256, 0, stream>>>(wu, wuT, HD, ID);
  tcvt_kernel<<<dim3(HD / 64, ID / 64, NE), 256, 0, stream>>>(wd, wdT, ID, HD);

  dim3 blk(512);
  dim3 gGU(ID / 128, 16, NE);    // 16 m-slots x 128 rows covers nCnt<=2048
  gu_gemm<<<gGU, blk, 0, stream>>>(xb, wgT, wuT, act, counts, list_ak);

  dim3 gD(HD / 128, 32, NE);     // y = 16 m-slots x 2 k-slices
  d_gemm<<<gD, blk, 0, stream>>>(act, wdT, yw, counts, list_ak, wlist);

  combine_kernel<<<1024, 256, 0, stream>>>(yw, out);
}